// Round 7
// baseline (329.349 us; speedup 1.0000x reference)
//
#include <hip/hip_runtime.h>

#define B 4
#define C 19
#define H 192
#define W 192
#define HW (H * W)
// 40 / ln(2): exp(-40*x) == exp2(-THETA_LOG2E*x)
#define THETA_LOG2E 57.70780163555855f

#define NT 768      // 12 waves
#define SEGS 12     // one wave per segment
#define SR 16       // rows per segment

// ---------------- setup: dmat = exp2(-theta*relu(edge)), plus transposed copy ----------------
__global__ __launch_bounds__(256) void k_prep(const float* __restrict__ edge,
                                              float* __restrict__ dmat,
                                              float* __restrict__ dmatT) {
    __shared__ float tile[32][33];
    int blk = blockIdx.x;                 // b*36 + ty*6 + tx
    int tx = blk % 6, ty = (blk / 6) % 6, b = blk / 36;
    int lx = threadIdx.x % 32, ly = threadIdx.x / 32;    // 32 x 8
    #pragma unroll
    for (int k = 0; k < 4; ++k) {
        int il = ly + k * 8;
        int I = ty * 32 + il, J = tx * 32 + lx;
        float e = edge[(b * H + I) * W + J];
        float d = exp2f(-THETA_LOG2E * fmaxf(e, 0.f));
        dmat[(b * H + I) * W + J] = d;
        tile[il][lx] = d;
    }
    __syncthreads();
    #pragma unroll
    for (int k = 0; k < 4; ++k) {
        int jl = ly + k * 8;
        dmatT[(b * W + tx * 32 + jl) * H + ty * 32 + lx] = tile[lx][jl];
    }
}

// ---------------- setup: dcol[b,i,j] = Zc + Sc - 1 (unit-f column scan) ----------------
__global__ __launch_bounds__(512) void k_dcol(const float* __restrict__ dmat,
                                              float* __restrict__ dcol) {
    const int DS = 8, DR = 24;            // 8 segments x 24 rows, 512 threads
    int blk = blockIdx.x;                 // b*3 + jt
    int jt = blk % 3, b = blk / 3;
    int jl = threadIdx.x & 63;
    int seg = threadIdx.x >> 6;
    int j = jl + jt * 64;
    int i0 = seg * DR;
    const float* dp = dmat + ((size_t)b * H + i0) * W + j;
    float* op = dcol + ((size_t)b * H + i0) * W + j;

    float dr[DR + 1];
    #pragma unroll
    for (int r = 0; r < DR; ++r) dr[r] = dp[r * W];
    dr[DR] = (seg < DS - 1) ? dp[DR * W] : 0.f;
    float Pf = 1.f, Qf = 0.f, Pb = 1.f, Qb = 0.f;
    #pragma unroll
    for (int r = 0; r < DR; ++r) { Qf = Qf * dr[r] + 1.f; Pf *= dr[r]; }
    #pragma unroll
    for (int r = DR - 1; r >= 0; --r) { Qb = Qb * dr[r + 1] + 1.f; Pb *= dr[r + 1]; }

    __shared__ float sPf[DS][64], sQf[DS][64], sPb[DS][64], sQb[DS][64];
    sPf[seg][jl] = Pf; sQf[seg][jl] = Qf;
    sPb[seg][jl] = Pb; sQb[seg][jl] = Qb;
    __syncthreads();
    if (seg == 0) {
        float P = sPf[0][jl], Q = sQf[0][jl];
        for (int s2 = 1; s2 < DS; ++s2) {
            float Pc = sPf[s2][jl], Qc = sQf[s2][jl];
            Q = Q * Pc + Qc; P = P * Pc;
            sPf[s2][jl] = P; sQf[s2][jl] = Q;
        }
    } else if (seg == 1) {
        float P = sPb[DS - 1][jl], Q = sQb[DS - 1][jl];
        for (int s2 = DS - 2; s2 >= 0; --s2) {
            float Pc = sPb[s2][jl], Qc = sQb[s2][jl];
            Q = Q * Pc + Qc; P = P * Pc;
            sPb[s2][jl] = P; sQb[s2][jl] = Q;
        }
    }
    __syncthreads();
    float z = (seg > 0) ? sQf[seg - 1][jl] : 0.f;
    float s = (seg < DS - 1) ? sQb[seg + 1][jl] : 0.f;
    float zarr[DR];
    #pragma unroll
    for (int r = 0; r < DR; ++r) { z = z * dr[r] + 1.f; zarr[r] = z; }
    #pragma unroll
    for (int r = DR - 1; r >= 0; --r) {
        s = s * dr[r + 1] + 1.f;
        op[r * W] = zarr[r] + s - 1.f;
    }
}

// ---------------- setup: rDg = 1 / (dcol + rowD - 1), rowD via in-register row scan ----------------
__global__ __launch_bounds__(256) void k_drow(const float* __restrict__ dmat,
                                              const float* __restrict__ dcol,
                                              float* __restrict__ rDg) {
    int wid = (blockIdx.x * 256 + threadIdx.x) >> 6;  // B*H = 768 waves
    int lane = threadIdx.x & 63;
    int i = wid % H, b = wid / H;
    int base = (b * H + i) * W;
    int s0 = 3 * lane;
    float d0 = dmat[base + s0], d1 = dmat[base + s0 + 1], d2 = dmat[base + s0 + 2];
    float d3 = (lane < 63) ? dmat[base + s0 + 3] : 0.f;

    float P = d0 * d1 * d2;
    float Q = d1 * d2 + d2 + 1.f;
    #pragma unroll
    for (int off = 1; off < 64; off <<= 1) {
        float Pp = __shfl_up(P, off);
        float Qp = __shfl_up(Q, off);
        if (lane >= off) { Q = Qp * P + Q; P = Pp * P; }
    }
    float zin = __shfl_up(Q, 1);
    if (lane == 0) zin = 0.f;
    float zA = zin * d0 + 1.f;
    float zB = zA * d1 + 1.f;
    float zC = zB * d2 + 1.f;

    float Pb = d3 * d2 * d1;
    float Qb = d2 * d1 + d1 + 1.f;
    #pragma unroll
    for (int off = 1; off < 64; off <<= 1) {
        float Pp = __shfl_down(Pb, off);
        float Qp = __shfl_down(Qb, off);
        if (lane < 64 - off) { Qb = Qp * Pb + Qb; Pb = Pp * Pb; }
    }
    float sin_ = __shfl_down(Qb, 1);
    if (lane == 63) sin_ = 0.f;
    float sC = sin_ * d3 + 1.f;
    float sB = sC * d2 + 1.f;
    float sA = sB * d1 + 1.f;

    rDg[base + s0]     = 1.f / (dcol[base + s0]     + zA + sA - 2.f);
    rDg[base + s0 + 1] = 1.f / (dcol[base + s0 + 1] + zB + sB - 2.f);
    rDg[base + s0 + 2] = 1.f / (dcol[base + s0 + 2] + zC + sC - 2.f);
}

// skewed LDS address: plane[i][j] stored at i*W + (i+j) mod W
// -> banks (i+j)%32: conflict-free for both "fixed i, lanes j" and "fixed j, lanes i"
__device__ __forceinline__ int paddr(int i, int c) {
    int cc = i + c;
    if (cc >= W) cc -= W;
    return i * W + cc;
}

// ---- col chunk: cs = Zc + Sc - f at (rows seg*SR.., col ch*64+lane); cs stays in REGISTERS ----
// FIRST: f comes from global (mask) and is also deposited into the plane for the row phase
template<bool FIRST>
__device__ __forceinline__ void col_chunk(float* plane, float2* scrF, float2* scrB,
                                          const float* dm, const float* fing,
                                          float (&cs)[SR], int lane, int seg, int ch) {
    const int r0 = seg * SR;
    const int j = ch * 64 + lane;
    float dr[SR + 1], fr[SR];
    #pragma unroll
    for (int r = 0; r < SR; ++r) dr[r] = dm[(r0 + r) * W + j];
    dr[SR] = (seg < SEGS - 1) ? dm[(r0 + SR) * W + j] : 0.f;
    if (FIRST) {
        #pragma unroll
        for (int r = 0; r < SR; ++r) {
            fr[r] = fing[(r0 + r) * W + j];
            plane[paddr(r0 + r, j)] = fr[r];
        }
    } else {
        #pragma unroll
        for (int r = 0; r < SR; ++r) fr[r] = plane[paddr(r0 + r, j)];
    }
    float Pf = 1.f, Qf = 0.f, Pb = 1.f, Qb = 0.f;
    #pragma unroll
    for (int r = 0; r < SR; ++r) { Qf = Qf * dr[r] + fr[r]; Pf *= dr[r]; }
    #pragma unroll
    for (int r = SR - 1; r >= 0; --r) { Qb = Qb * dr[r + 1] + fr[r]; Pb *= dr[r + 1]; }
    __syncthreads();                       // previous chunk's scr reads complete
    scrF[seg * 64 + lane] = make_float2(Pf, Qf);
    scrB[seg * 64 + lane] = make_float2(Pb, Qb);
    __syncthreads();
    // self-service compose: each thread folds its own prefix/suffix (wave-uniform trip count)
    float z = 0.f, s = 0.f;
    for (int s2 = 0; s2 < seg; ++s2) { float2 v = scrF[s2 * 64 + lane]; z = z * v.x + v.y; }
    for (int s2 = SEGS - 1; s2 > seg; --s2) { float2 v = scrB[s2 * 64 + lane]; s = s * v.x + v.y; }
    float zarr[SR];
    #pragma unroll
    for (int r = 0; r < SR; ++r) { z = z * dr[r] + fr[r]; zarr[r] = z; }
    #pragma unroll
    for (int r = SR - 1; r >= 0; --r) {
        s = s * dr[r + 1] + fr[r];
        cs[r] = zarr[r] + s - fr[r];
    }
}

// ---- row chunk: plane <- rowpart = Zr + Sr - 2f at (row ch*64+lane, cols seg*SR..) ----
__device__ __forceinline__ void row_chunk(float* plane, float2* scrF, float2* scrB,
                                          const float* dmT, int lane, int seg, int ch) {
    const int r0 = seg * SR;
    const int i = ch * 64 + lane;
    float dr[SR + 1], fr[SR];
    #pragma unroll
    for (int r = 0; r < SR; ++r) dr[r] = dmT[(r0 + r) * H + i];   // d[i][r0+r], lanes i coalesced
    dr[SR] = (seg < SEGS - 1) ? dmT[(r0 + SR) * H + i] : 0.f;
    #pragma unroll
    for (int r = 0; r < SR; ++r) fr[r] = plane[paddr(i, r0 + r)];
    float Pf = 1.f, Qf = 0.f, Pb = 1.f, Qb = 0.f;
    #pragma unroll
    for (int r = 0; r < SR; ++r) { Qf = Qf * dr[r] + fr[r]; Pf *= dr[r]; }
    #pragma unroll
    for (int r = SR - 1; r >= 0; --r) { Qb = Qb * dr[r + 1] + fr[r]; Pb *= dr[r + 1]; }
    __syncthreads();
    scrF[seg * 64 + lane] = make_float2(Pf, Qf);
    scrB[seg * 64 + lane] = make_float2(Pb, Qb);
    __syncthreads();
    float z = 0.f, s = 0.f;
    for (int s2 = 0; s2 < seg; ++s2) { float2 v = scrF[s2 * 64 + lane]; z = z * v.x + v.y; }
    for (int s2 = SEGS - 1; s2 > seg; --s2) { float2 v = scrB[s2 * 64 + lane]; s = s * v.x + v.y; }
    float zarr[SR];
    #pragma unroll
    for (int r = 0; r < SR; ++r) { z = z * dr[r] + fr[r]; zarr[r] = z; }
    #pragma unroll
    for (int r = SR - 1; r >= 0; --r) {
        s = s * dr[r + 1] + fr[r];
        plane[paddr(i, r0 + r)] = zarr[r] + s - 2.f * fr[r];
    }
}

// ---- combine chunk (same ownership as col chunk -> cs from registers) ----
// FINAL: write to global out instead of back into the plane
template<bool FINAL>
__device__ __forceinline__ void combine_chunk(float* plane, const float* rDp,
                                              float* outp, float (&cs)[SR],
                                              int lane, int seg, int ch) {
    const int r0 = seg * SR;
    const int j = ch * 64 + lane;
    #pragma unroll
    for (int r = 0; r < SR; ++r) {
        float v = (plane[paddr(r0 + r, j)] + cs[r]) * rDp[(r0 + r) * W + j];
        if (FINAL) outp[(r0 + r) * W + j] = v;
        else       plane[paddr(r0 + r, j)] = v;
    }
}

// ---------------- fused: 3 iterations for one (b,c) plane ----------------
__global__ __launch_bounds__(NT, 3) void k_fused(const float* __restrict__ mask,
                                                 const float* __restrict__ dmatg,
                                                 const float* __restrict__ dmatTg,
                                                 const float* __restrict__ rDg,
                                                 float* __restrict__ outg) {
    __shared__ float plane[H * W];           // 147456 B (skewed layout)
    __shared__ float2 scrF[SEGS * 64];       // 6144 B
    __shared__ float2 scrB[SEGS * 64];       // 6144 B   (total 159744 <= 163840)

    const int t = threadIdx.x, lane = t & 63, seg = t >> 6;
    const int bc = blockIdx.x;
    const int b = bc / C;
    const float* dm  = dmatg + b * HW;
    const float* dmT = dmatTg + b * HW;
    const float* rDp = rDg + b * HW;
    const float* fin = mask + (size_t)bc * HW;
    float* outp = outg + (size_t)bc * HW;

    float cs0[SR], cs1[SR], cs2[SR];         // colsum, held in registers across the row phase

    // ===== iter 0 (f = mask, loaded from global; deposited into plane for the row phase) =====
    col_chunk<true>(plane, scrF, scrB, dm, fin, cs0, lane, seg, 0);
    col_chunk<true>(plane, scrF, scrB, dm, fin, cs1, lane, seg, 1);
    col_chunk<true>(plane, scrF, scrB, dm, fin, cs2, lane, seg, 2);
    __syncthreads();
    row_chunk(plane, scrF, scrB, dmT, lane, seg, 0);
    row_chunk(plane, scrF, scrB, dmT, lane, seg, 1);
    row_chunk(plane, scrF, scrB, dmT, lane, seg, 2);
    __syncthreads();
    combine_chunk<false>(plane, rDp, nullptr, cs0, lane, seg, 0);
    combine_chunk<false>(plane, rDp, nullptr, cs1, lane, seg, 1);
    combine_chunk<false>(plane, rDp, nullptr, cs2, lane, seg, 2);
    // no barrier needed: next col phase reads exactly the elements this thread just wrote

    // ===== iter 1 =====
    col_chunk<false>(plane, scrF, scrB, dm, nullptr, cs0, lane, seg, 0);
    col_chunk<false>(plane, scrF, scrB, dm, nullptr, cs1, lane, seg, 1);
    col_chunk<false>(plane, scrF, scrB, dm, nullptr, cs2, lane, seg, 2);
    __syncthreads();
    row_chunk(plane, scrF, scrB, dmT, lane, seg, 0);
    row_chunk(plane, scrF, scrB, dmT, lane, seg, 1);
    row_chunk(plane, scrF, scrB, dmT, lane, seg, 2);
    __syncthreads();
    combine_chunk<false>(plane, rDp, nullptr, cs0, lane, seg, 0);
    combine_chunk<false>(plane, rDp, nullptr, cs1, lane, seg, 1);
    combine_chunk<false>(plane, rDp, nullptr, cs2, lane, seg, 2);

    // ===== iter 2 (final combine streams straight to d_out) =====
    col_chunk<false>(plane, scrF, scrB, dm, nullptr, cs0, lane, seg, 0);
    col_chunk<false>(plane, scrF, scrB, dm, nullptr, cs1, lane, seg, 1);
    col_chunk<false>(plane, scrF, scrB, dm, nullptr, cs2, lane, seg, 2);
    __syncthreads();
    row_chunk(plane, scrF, scrB, dmT, lane, seg, 0);
    row_chunk(plane, scrF, scrB, dmT, lane, seg, 1);
    row_chunk(plane, scrF, scrB, dmT, lane, seg, 2);
    __syncthreads();
    combine_chunk<true>(plane, rDp, outp, cs0, lane, seg, 0);
    combine_chunk<true>(plane, rDp, outp, cs1, lane, seg, 1);
    combine_chunk<true>(plane, rDp, outp, cs2, lane, seg, 2);
}

extern "C" void kernel_launch(void* const* d_in, const int* in_sizes, int n_in,
                              void* d_out, int out_size, void* d_ws, size_t ws_size,
                              hipStream_t stream) {
    const float* mask = (const float*)d_in[0];
    const float* edge = (const float*)d_in[1];
    float* out = (float*)d_out;

    float* dmat  = (float*)d_ws;            // [B,H,W]
    float* dmatT = dmat + B * HW;           // [B,W,H]
    float* dcol  = dmatT + B * HW;          // [B,H,W]
    float* rDg   = dcol + B * HW;           // [B,H,W]

    k_prep<<<B * 36, 256, 0, stream>>>(edge, dmat, dmatT);
    k_dcol<<<B * 3, 512, 0, stream>>>(dmat, dcol);
    k_drow<<<(B * H) / 4, 256, 0, stream>>>(dmat, dcol, rDg);
    k_fused<<<B * C, NT, 0, stream>>>(mask, dmat, dmatT, rDg, out);
}

// Round 8
// 322.130 us; speedup vs baseline: 1.0224x; 1.0224x over previous
//
#include <hip/hip_runtime.h>

#define B 4
#define C 19
#define H 192
#define W 192
#define HW (H * W)
// 40 / ln(2): exp(-40*x) == exp2(-THETA_LOG2E*x)
#define THETA_LOG2E 57.70780163555855f

#define NT 1024     // 16 waves, 1 block/CU
#define SEGS 16     // one wave per segment
#define SR 12       // rows per segment (16*12 = 192)

// ---------------- setup: dmat = exp2(-theta*relu(edge)), plus transposed copy ----------------
__global__ __launch_bounds__(256) void k_prep(const float* __restrict__ edge,
                                              float* __restrict__ dmat,
                                              float* __restrict__ dmatT) {
    __shared__ float tile[32][33];
    int blk = blockIdx.x;                 // b*36 + ty*6 + tx
    int tx = blk % 6, ty = (blk / 6) % 6, b = blk / 36;
    int lx = threadIdx.x % 32, ly = threadIdx.x / 32;    // 32 x 8
    #pragma unroll
    for (int k = 0; k < 4; ++k) {
        int il = ly + k * 8;
        int I = ty * 32 + il, J = tx * 32 + lx;
        float e = edge[(b * H + I) * W + J];
        float d = exp2f(-THETA_LOG2E * fmaxf(e, 0.f));
        dmat[(b * H + I) * W + J] = d;
        tile[il][lx] = d;
    }
    __syncthreads();
    #pragma unroll
    for (int k = 0; k < 4; ++k) {
        int jl = ly + k * 8;
        dmatT[(b * W + tx * 32 + jl) * H + ty * 32 + lx] = tile[lx][jl];
    }
}

// ---------------- setup: dcol[b,i,j] = Zc + Sc - 1 (unit-f column scan) ----------------
__global__ __launch_bounds__(512) void k_dcol(const float* __restrict__ dmat,
                                              float* __restrict__ dcol) {
    const int DS = 8, DR = 24;            // 8 segments x 24 rows, 512 threads
    int blk = blockIdx.x;                 // b*3 + jt
    int jt = blk % 3, b = blk / 3;
    int jl = threadIdx.x & 63;
    int seg = threadIdx.x >> 6;
    int j = jl + jt * 64;
    int i0 = seg * DR;
    const float* dp = dmat + ((size_t)b * H + i0) * W + j;
    float* op = dcol + ((size_t)b * H + i0) * W + j;

    float dr[DR + 1];
    #pragma unroll
    for (int r = 0; r < DR; ++r) dr[r] = dp[r * W];
    dr[DR] = (seg < DS - 1) ? dp[DR * W] : 0.f;
    float Pf = 1.f, Qf = 0.f, Pb = 1.f, Qb = 0.f;
    #pragma unroll
    for (int r = 0; r < DR; ++r) { Qf = Qf * dr[r] + 1.f; Pf *= dr[r]; }
    #pragma unroll
    for (int r = DR - 1; r >= 0; --r) { Qb = Qb * dr[r + 1] + 1.f; Pb *= dr[r + 1]; }

    __shared__ float sPf[DS][64], sQf[DS][64], sPb[DS][64], sQb[DS][64];
    sPf[seg][jl] = Pf; sQf[seg][jl] = Qf;
    sPb[seg][jl] = Pb; sQb[seg][jl] = Qb;
    __syncthreads();
    if (seg == 0) {
        float P = sPf[0][jl], Q = sQf[0][jl];
        for (int s2 = 1; s2 < DS; ++s2) {
            float Pc = sPf[s2][jl], Qc = sQf[s2][jl];
            Q = Q * Pc + Qc; P = P * Pc;
            sPf[s2][jl] = P; sQf[s2][jl] = Q;
        }
    } else if (seg == 1) {
        float P = sPb[DS - 1][jl], Q = sQb[DS - 1][jl];
        for (int s2 = DS - 2; s2 >= 0; --s2) {
            float Pc = sPb[s2][jl], Qc = sQb[s2][jl];
            Q = Q * Pc + Qc; P = P * Pc;
            sPb[s2][jl] = P; sQb[s2][jl] = Q;
        }
    }
    __syncthreads();
    float z = (seg > 0) ? sQf[seg - 1][jl] : 0.f;
    float s = (seg < DS - 1) ? sQb[seg + 1][jl] : 0.f;
    float zarr[DR];
    #pragma unroll
    for (int r = 0; r < DR; ++r) { z = z * dr[r] + 1.f; zarr[r] = z; }
    #pragma unroll
    for (int r = DR - 1; r >= 0; --r) {
        s = s * dr[r + 1] + 1.f;
        op[r * W] = zarr[r] + s - 1.f;
    }
}

// ---------------- setup: rDg = 1 / (dcol + rowD - 1), rowD via in-register row scan ----------------
__global__ __launch_bounds__(256) void k_drow(const float* __restrict__ dmat,
                                              const float* __restrict__ dcol,
                                              float* __restrict__ rDg) {
    int wid = (blockIdx.x * 256 + threadIdx.x) >> 6;  // B*H = 768 waves
    int lane = threadIdx.x & 63;
    int i = wid % H, b = wid / H;
    int base = (b * H + i) * W;
    int s0 = 3 * lane;
    float d0 = dmat[base + s0], d1 = dmat[base + s0 + 1], d2 = dmat[base + s0 + 2];
    float d3 = (lane < 63) ? dmat[base + s0 + 3] : 0.f;

    float P = d0 * d1 * d2;
    float Q = d1 * d2 + d2 + 1.f;
    #pragma unroll
    for (int off = 1; off < 64; off <<= 1) {
        float Pp = __shfl_up(P, off);
        float Qp = __shfl_up(Q, off);
        if (lane >= off) { Q = Qp * P + Q; P = Pp * P; }
    }
    float zin = __shfl_up(Q, 1);
    if (lane == 0) zin = 0.f;
    float zA = zin * d0 + 1.f;
    float zB = zA * d1 + 1.f;
    float zC = zB * d2 + 1.f;

    float Pb = d3 * d2 * d1;
    float Qb = d2 * d1 + d1 + 1.f;
    #pragma unroll
    for (int off = 1; off < 64; off <<= 1) {
        float Pp = __shfl_down(Pb, off);
        float Qp = __shfl_down(Qb, off);
        if (lane < 64 - off) { Qb = Qp * Pb + Qb; Pb = Pp * Pb; }
    }
    float sin_ = __shfl_down(Qb, 1);
    if (lane == 63) sin_ = 0.f;
    float sC = sin_ * d3 + 1.f;
    float sB = sC * d2 + 1.f;
    float sA = sB * d1 + 1.f;

    rDg[base + s0]     = 1.f / (dcol[base + s0]     + zA + sA - 2.f);
    rDg[base + s0 + 1] = 1.f / (dcol[base + s0 + 1] + zB + sB - 2.f);
    rDg[base + s0 + 2] = 1.f / (dcol[base + s0 + 2] + zC + sC - 2.f);
}

// skewed LDS address: plane[i][j] stored at i*W + (i+j) mod W
// -> banks (i+j)%32: conflict-free for both "fixed i, lanes j" and "fixed j, lanes i"
#define PADDR(i, c) ({ int _cc = (i) + (c); if (_cc >= W) _cc -= W; (i) * W + _cc; })

// ---- col chunk: CS[r] = Zc + Sc - f at (rows r0.., col CH*64+lane); CS stays in registers ----
#define COL_CHUNK(CS, CH, LOADF)                                                      \
  {                                                                                   \
    const int j = (CH) * 64 + lane;                                                   \
    float dr[SR + 1], fr[SR];                                                         \
    _Pragma("unroll")                                                                 \
    for (int r = 0; r < SR; ++r) dr[r] = dm[(r0 + r) * W + j];                        \
    dr[SR] = (seg < SEGS - 1) ? dm[(r0 + SR) * W + j] : 0.f;                          \
    LOADF                                                                             \
    float Pf = 1.f, Qf = 0.f, Pb = 1.f, Qb = 0.f;                                     \
    _Pragma("unroll")                                                                 \
    for (int r = 0; r < SR; ++r) { Qf = Qf * dr[r] + fr[r]; Pf *= dr[r]; }            \
    _Pragma("unroll")                                                                 \
    for (int r = SR - 1; r >= 0; --r) { Qb = Qb * dr[r + 1] + fr[r]; Pb *= dr[r + 1]; } \
    __syncthreads();                                                                  \
    scrF[seg * 64 + lane] = make_float2(Pf, Qf);                                      \
    scrB[seg * 64 + lane] = make_float2(Pb, Qb);                                      \
    __syncthreads();                                                                  \
    float z = 0.f, s = 0.f;                                                           \
    for (int s2 = 0; s2 < seg; ++s2) { float2 v = scrF[s2 * 64 + lane]; z = z * v.x + v.y; } \
    for (int s2 = SEGS - 1; s2 > seg; --s2) { float2 v = scrB[s2 * 64 + lane]; s = s * v.x + v.y; } \
    _Pragma("unroll")                                                                 \
    for (int r = 0; r < SR; ++r) { z = z * dr[r] + fr[r]; CS[r] = z; }                \
    _Pragma("unroll")                                                                 \
    for (int r = SR - 1; r >= 0; --r) { s = s * dr[r + 1] + fr[r]; CS[r] += s - fr[r]; } \
  }

#define LOADF_GLOBAL                                                                  \
    _Pragma("unroll")                                                                 \
    for (int r = 0; r < SR; ++r) { fr[r] = fin[(r0 + r) * W + j]; plane[PADDR(r0 + r, j)] = fr[r]; }

#define LOADF_PLANE                                                                   \
    _Pragma("unroll")                                                                 \
    for (int r = 0; r < SR; ++r) fr[r] = plane[PADDR(r0 + r, j)];

// ---- row chunk: plane <- Zr + Sr - 2f at (row CH*64+lane, cols r0..) ----
// fwd walk writes z - 2f; bwd walk adds s in place (no zarr -> fewer live regs)
#define ROW_CHUNK(CH)                                                                 \
  {                                                                                   \
    const int i = (CH) * 64 + lane;                                                   \
    float dr[SR + 1], fr[SR];                                                         \
    _Pragma("unroll")                                                                 \
    for (int r = 0; r < SR; ++r) dr[r] = dmT[(r0 + r) * H + i];                       \
    dr[SR] = (seg < SEGS - 1) ? dmT[(r0 + SR) * H + i] : 0.f;                         \
    _Pragma("unroll")                                                                 \
    for (int r = 0; r < SR; ++r) fr[r] = plane[PADDR(i, r0 + r)];                     \
    float Pf = 1.f, Qf = 0.f, Pb = 1.f, Qb = 0.f;                                     \
    _Pragma("unroll")                                                                 \
    for (int r = 0; r < SR; ++r) { Qf = Qf * dr[r] + fr[r]; Pf *= dr[r]; }            \
    _Pragma("unroll")                                                                 \
    for (int r = SR - 1; r >= 0; --r) { Qb = Qb * dr[r + 1] + fr[r]; Pb *= dr[r + 1]; } \
    __syncthreads();                                                                  \
    scrF[seg * 64 + lane] = make_float2(Pf, Qf);                                      \
    scrB[seg * 64 + lane] = make_float2(Pb, Qb);                                      \
    __syncthreads();                                                                  \
    float z = 0.f, s = 0.f;                                                           \
    for (int s2 = 0; s2 < seg; ++s2) { float2 v = scrF[s2 * 64 + lane]; z = z * v.x + v.y; } \
    for (int s2 = SEGS - 1; s2 > seg; --s2) { float2 v = scrB[s2 * 64 + lane]; s = s * v.x + v.y; } \
    _Pragma("unroll")                                                                 \
    for (int r = 0; r < SR; ++r) { z = z * dr[r] + fr[r]; plane[PADDR(i, r0 + r)] = z - 2.f * fr[r]; } \
    _Pragma("unroll")                                                                 \
    for (int r = SR - 1; r >= 0; --r) { s = s * dr[r + 1] + fr[r]; plane[PADDR(i, r0 + r)] += s; } \
  }

// ---- combine chunk (same ownership as col chunk): dest = (plane + CS) * rD ----
#define COMBINE_CHUNK(CS, CH, STORE)                                                  \
  {                                                                                   \
    const int j = (CH) * 64 + lane;                                                   \
    _Pragma("unroll")                                                                 \
    for (int r = 0; r < SR; ++r) {                                                    \
        float v = (plane[PADDR(r0 + r, j)] + CS[r]) * rDp[(r0 + r) * W + j];          \
        STORE                                                                         \
    }                                                                                 \
  }

#define STORE_PLANE plane[PADDR(r0 + r, j)] = v;
#define STORE_OUT   outp[(r0 + r) * W + j] = v;

// ---------------- fused: 3 iterations for one (b,c) plane ----------------
__global__ __launch_bounds__(NT, 4) void k_fused(const float* __restrict__ mask,
                                                 const float* __restrict__ dmatg,
                                                 const float* __restrict__ dmatTg,
                                                 const float* __restrict__ rDg,
                                                 float* __restrict__ outg) {
    __shared__ float plane[H * W];           // 147456 B (skewed layout)
    __shared__ float2 scrF[SEGS * 64];       // 8192 B
    __shared__ float2 scrB[SEGS * 64];       // 8192 B   (total 163840 = 160 KiB exactly)

    const int t = threadIdx.x, lane = t & 63, seg = t >> 6;
    const int r0 = seg * SR;
    const int bc = blockIdx.x;
    const int b = bc / C;
    const float* dm  = dmatg + b * HW;
    const float* dmT = dmatTg + b * HW;
    const float* rDp = rDg + b * HW;
    const float* fin = mask + (size_t)bc * HW;
    float* outp = outg + (size_t)bc * HW;

    float cs0[SR], cs1[SR], cs2[SR];         // colsum, 36 floats held across the row phase

    // ===== iter 0 (f = mask from global, deposited into plane) =====
    COL_CHUNK(cs0, 0, LOADF_GLOBAL)
    COL_CHUNK(cs1, 1, LOADF_GLOBAL)
    COL_CHUNK(cs2, 2, LOADF_GLOBAL)
    __syncthreads();
    ROW_CHUNK(0)
    ROW_CHUNK(1)
    ROW_CHUNK(2)
    __syncthreads();
    COMBINE_CHUNK(cs0, 0, STORE_PLANE)
    COMBINE_CHUNK(cs1, 1, STORE_PLANE)
    COMBINE_CHUNK(cs2, 2, STORE_PLANE)
    // no barrier: next col phase reads exactly what this thread just wrote

    // ===== iter 1 =====
    COL_CHUNK(cs0, 0, LOADF_PLANE)
    COL_CHUNK(cs1, 1, LOADF_PLANE)
    COL_CHUNK(cs2, 2, LOADF_PLANE)
    __syncthreads();
    ROW_CHUNK(0)
    ROW_CHUNK(1)
    ROW_CHUNK(2)
    __syncthreads();
    COMBINE_CHUNK(cs0, 0, STORE_PLANE)
    COMBINE_CHUNK(cs1, 1, STORE_PLANE)
    COMBINE_CHUNK(cs2, 2, STORE_PLANE)

    // ===== iter 2 (final combine streams straight to d_out) =====
    COL_CHUNK(cs0, 0, LOADF_PLANE)
    COL_CHUNK(cs1, 1, LOADF_PLANE)
    COL_CHUNK(cs2, 2, LOADF_PLANE)
    __syncthreads();
    ROW_CHUNK(0)
    ROW_CHUNK(1)
    ROW_CHUNK(2)
    __syncthreads();
    COMBINE_CHUNK(cs0, 0, STORE_OUT)
    COMBINE_CHUNK(cs1, 1, STORE_OUT)
    COMBINE_CHUNK(cs2, 2, STORE_OUT)
}

extern "C" void kernel_launch(void* const* d_in, const int* in_sizes, int n_in,
                              void* d_out, int out_size, void* d_ws, size_t ws_size,
                              hipStream_t stream) {
    const float* mask = (const float*)d_in[0];
    const float* edge = (const float*)d_in[1];
    float* out = (float*)d_out;

    float* dmat  = (float*)d_ws;            // [B,H,W]
    float* dmatT = dmat + B * HW;           // [B,W,H]
    float* dcol  = dmatT + B * HW;          // [B,H,W]
    float* rDg   = dcol + B * HW;           // [B,H,W]

    k_prep<<<B * 36, 256, 0, stream>>>(edge, dmat, dmatT);
    k_dcol<<<B * 3, 512, 0, stream>>>(dmat, dcol);
    k_drow<<<(B * H) / 4, 256, 0, stream>>>(dmat, dcol, rDg);
    k_fused<<<B * C, NT, 0, stream>>>(mask, dmat, dmatT, rDg, out);
}

// Round 9
// 57.334 us; speedup vs baseline: 5.7444x; 5.6185x over previous
//
#include <hip/hip_runtime.h>

#define B 4
#define C 19
#define H 192
#define W 192
#define HW (H * W)
// 40 / ln(2): exp(-40*x) == exp2(-THETA_LOG2E*x)
#define THETA_LOG2E 57.70780163555855f

#define CSEGS 8
#define CSR 24     // rows per segment in the column-scan kernel

// ================= column scan kernel =================
// colsum[b,c,i,j] = Zc + Sc - f  (bidirectional first-order recurrence down each column)
// d computed on the fly from edge (coalesced: lane = j, stride-W rows).
// DENOM: c==0 blocks additionally run the unit-f scan -> dcol[b,i,j] (for the softmax denominator).
template<bool DENOM>
__global__ __launch_bounds__(512) void k_col(const float* __restrict__ fin,
                                             const float* __restrict__ edge,
                                             float* __restrict__ csum,
                                             float* __restrict__ dcolg) {
    int blk = blockIdx.x;                  // (b*C + c)*3 + jt
    int jt = blk % 3;
    int bc = blk / 3;
    int b = bc / C;
    int c = bc % C;
    int jl = threadIdx.x & 63, seg = threadIdx.x >> 6;
    int j = jt * 64 + jl;
    int i0 = seg * CSR;

    const float* ep = edge + ((size_t)b * H + i0) * W + j;
    const float* fp = fin + ((size_t)bc * H + i0) * W + j;
    float* op = csum + ((size_t)bc * H + i0) * W + j;

    float dr[CSR + 1], fr[CSR];
    #pragma unroll
    for (int r = 0; r < CSR; ++r) {
        float e = ep[r * W];
        dr[r] = exp2f(-THETA_LOG2E * fmaxf(e, 0.f));
        fr[r] = fp[r * W];
    }
    if (seg < CSEGS - 1) {
        float e = ep[CSR * W];
        dr[CSR] = exp2f(-THETA_LOG2E * fmaxf(e, 0.f));
    } else {
        dr[CSR] = 0.f;
    }

    __shared__ float sPf[CSEGS][64], sQf[CSEGS][64], sPb[CSEGS][64], sQb[CSEGS][64];

    // per-segment affine transforms
    float Pf = 1.f, Qf = 0.f, Pb = 1.f, Qb = 0.f;
    #pragma unroll
    for (int r = 0; r < CSR; ++r) { Qf = Qf * dr[r] + fr[r]; Pf *= dr[r]; }
    #pragma unroll
    for (int r = CSR - 1; r >= 0; --r) { Qb = Qb * dr[r + 1] + fr[r]; Pb *= dr[r + 1]; }
    sPf[seg][jl] = Pf; sQf[seg][jl] = Qf;
    sPb[seg][jl] = Pb; sQb[seg][jl] = Qb;
    __syncthreads();
    if (seg == 0) {          // inclusive prefix transforms
        float P = sPf[0][jl], Q = sQf[0][jl];
        for (int s2 = 1; s2 < CSEGS; ++s2) {
            float Pc = sPf[s2][jl], Qc = sQf[s2][jl];
            Q = Q * Pc + Qc; P = P * Pc;
            sPf[s2][jl] = P; sQf[s2][jl] = Q;
        }
    } else if (seg == 1) {   // inclusive suffix transforms
        float P = sPb[CSEGS - 1][jl], Q = sQb[CSEGS - 1][jl];
        for (int s2 = CSEGS - 2; s2 >= 0; --s2) {
            float Pc = sPb[s2][jl], Qc = sQb[s2][jl];
            Q = Q * Pc + Qc; P = P * Pc;
            sPb[s2][jl] = P; sQb[s2][jl] = Q;
        }
    }
    __syncthreads();
    float z = (seg > 0) ? sQf[seg - 1][jl] : 0.f;
    float s = (seg < CSEGS - 1) ? sQb[seg + 1][jl] : 0.f;
    float zarr[CSR];
    #pragma unroll
    for (int r = 0; r < CSR; ++r) { z = z * dr[r] + fr[r]; zarr[r] = z; }
    #pragma unroll
    for (int r = CSR - 1; r >= 0; --r) {
        s = s * dr[r + 1] + fr[r];
        op[r * W] = zarr[r] + s - fr[r];     // diagonal counted once
    }

    if (DENOM && c == 0) {
        // unit-f scan for the denominator column part: dcol = Zu + Su - 1
        float Pf2 = 1.f, Qf2 = 0.f, Pb2 = 1.f, Qb2 = 0.f;
        #pragma unroll
        for (int r = 0; r < CSR; ++r) { Qf2 = Qf2 * dr[r] + 1.f; Pf2 *= dr[r]; }
        #pragma unroll
        for (int r = CSR - 1; r >= 0; --r) { Qb2 = Qb2 * dr[r + 1] + 1.f; Pb2 *= dr[r + 1]; }
        __syncthreads();     // previous boundary reads done before scr overwrite
        sPf[seg][jl] = Pf2; sQf[seg][jl] = Qf2;
        sPb[seg][jl] = Pb2; sQb[seg][jl] = Qb2;
        __syncthreads();
        if (seg == 0) {
            float P = sPf[0][jl], Q = sQf[0][jl];
            for (int s2 = 1; s2 < CSEGS; ++s2) {
                float Pc = sPf[s2][jl], Qc = sQf[s2][jl];
                Q = Q * Pc + Qc; P = P * Pc;
                sPf[s2][jl] = P; sQf[s2][jl] = Q;
            }
        } else if (seg == 1) {
            float P = sPb[CSEGS - 1][jl], Q = sQb[CSEGS - 1][jl];
            for (int s2 = CSEGS - 2; s2 >= 0; --s2) {
                float Pc = sPb[s2][jl], Qc = sQb[s2][jl];
                Q = Q * Pc + Qc; P = P * Pc;
                sPb[s2][jl] = P; sQb[s2][jl] = Q;
            }
        }
        __syncthreads();
        float zu = (seg > 0) ? sQf[seg - 1][jl] : 0.f;
        float su = (seg < CSEGS - 1) ? sQb[seg + 1][jl] : 0.f;
        float* dop = dcolg + ((size_t)b * H + i0) * W + j;
        #pragma unroll
        for (int r = 0; r < CSR; ++r) { zu = zu * dr[r] + 1.f; zarr[r] = zu; }
        #pragma unroll
        for (int r = CSR - 1; r >= 0; --r) {
            su = su * dr[r + 1] + 1.f;
            dop[r * W] = zarr[r] + su - 1.f;
        }
    }
}

// ================= row scan + combine kernel =================
// wave per (b,c,i); lane owns s = {3l, 3l+1, 3l+2}; in-register Kogge-Stone over affine pairs.
// out = (csum + Zr + Sr - 2f) * rD.   FIRST: also compute unit row scan -> rD, store (c==0).
// fin may alias fout (each thread reads its 3 elements before writing them).
template<bool FIRST>
__global__ __launch_bounds__(256) void k_row(const float* fin,
                                             float* fout,
                                             const float* __restrict__ edge,
                                             const float* __restrict__ csum,
                                             const float* __restrict__ dcolg,
                                             float* __restrict__ rDg) {
    int wid = (blockIdx.x * 256 + threadIdx.x) >> 6;   // B*C*H = 14592 waves
    int lane = threadIdx.x & 63;
    int i = wid % H;
    int c = (wid / H) % C;
    int b = wid / (H * C);
    const size_t rb = ((size_t)(b * C + c) * H + i) * W;
    const int db = (b * H + i) * W;
    const int s0 = 3 * lane;

    float e0 = edge[db + s0], e1 = edge[db + s0 + 1], e2 = edge[db + s0 + 2];
    float d0 = exp2f(-THETA_LOG2E * fmaxf(e0, 0.f));
    float d1 = exp2f(-THETA_LOG2E * fmaxf(e1, 0.f));
    float d2 = exp2f(-THETA_LOG2E * fmaxf(e2, 0.f));
    float d3 = 0.f;
    if (lane < 63) {
        float e3 = edge[db + s0 + 3];
        d3 = exp2f(-THETA_LOG2E * fmaxf(e3, 0.f));
    }
    float f0 = fin[rb + s0], f1 = fin[rb + s0 + 1], f2 = fin[rb + s0 + 2];

    // ---- forward scan: Z[s] = d[s]*Z[s-1] + f[s]
    float P = d0 * d1 * d2;
    float Q = (f0 * d1 + f1) * d2 + f2;
    #pragma unroll
    for (int off = 1; off < 64; off <<= 1) {
        float Pp = __shfl_up(P, off);
        float Qp = __shfl_up(Q, off);
        if (lane >= off) { Q = Qp * P + Q; P = Pp * P; }
    }
    float zin = __shfl_up(Q, 1);
    if (lane == 0) zin = 0.f;
    float zA = zin * d0 + f0;
    float zB = zA * d1 + f1;
    float zC = zB * d2 + f2;

    // ---- backward scan: Sf[s] = d[s+1]*Sf[s+1] + f[s]
    float Pb = d3 * d2 * d1;
    float Qb = (f2 * d2 + f1) * d1 + f0;
    #pragma unroll
    for (int off = 1; off < 64; off <<= 1) {
        float Pp = __shfl_down(Pb, off);
        float Qp = __shfl_down(Qb, off);
        if (lane < 64 - off) { Qb = Qp * Pb + Qb; Pb = Pp * Pb; }
    }
    float sin_ = __shfl_down(Qb, 1);
    if (lane == 63) sin_ = 0.f;
    float sC = sin_ * d3 + f2;
    float sB = sC * d2 + f1;
    float sA = sB * d1 + f0;

    // ---- rD: iteration 0 computes it (unit scans + dcol), later iterations load it
    float rd0, rd1, rd2;
    if (FIRST) {
        float Pu = d0 * d1 * d2;
        float Qu = d1 * d2 + d2 + 1.f;
        #pragma unroll
        for (int off = 1; off < 64; off <<= 1) {
            float Pp = __shfl_up(Pu, off);
            float Qp = __shfl_up(Qu, off);
            if (lane >= off) { Qu = Qp * Pu + Qu; Pu = Pp * Pu; }
        }
        float zuin = __shfl_up(Qu, 1);
        if (lane == 0) zuin = 0.f;
        float zuA = zuin * d0 + 1.f;
        float zuB = zuA * d1 + 1.f;
        float zuC = zuB * d2 + 1.f;

        float Pub = d3 * d2 * d1;
        float Qub = d2 * d1 + d1 + 1.f;
        #pragma unroll
        for (int off = 1; off < 64; off <<= 1) {
            float Pp = __shfl_down(Pub, off);
            float Qp = __shfl_down(Qub, off);
            if (lane < 64 - off) { Qub = Qp * Pub + Qub; Pub = Pp * Pub; }
        }
        float suin = __shfl_down(Qub, 1);
        if (lane == 63) suin = 0.f;
        float suC = suin * d3 + 1.f;
        float suB = suC * d2 + 1.f;
        float suA = suB * d1 + 1.f;

        // D = dcol + (Zu + Su - 1) - 1
        rd0 = 1.f / (dcolg[db + s0]     + zuA + suA - 2.f);
        rd1 = 1.f / (dcolg[db + s0 + 1] + zuB + suB - 2.f);
        rd2 = 1.f / (dcolg[db + s0 + 2] + zuC + suC - 2.f);
        if (c == 0) {
            rDg[db + s0]     = rd0;
            rDg[db + s0 + 1] = rd1;
            rDg[db + s0 + 2] = rd2;
        }
    } else {
        rd0 = rDg[db + s0];
        rd1 = rDg[db + s0 + 1];
        rd2 = rDg[db + s0 + 2];
    }

    // ---- combine: out = (colsum + rowZ + rowS - 2f) * rD
    float cs0 = csum[rb + s0], cs1 = csum[rb + s0 + 1], cs2 = csum[rb + s0 + 2];
    fout[rb + s0]     = (cs0 + zA + sA - 2.f * f0) * rd0;
    fout[rb + s0 + 1] = (cs1 + zB + sB - 2.f * f1) * rd1;
    fout[rb + s0 + 2] = (cs2 + zC + sC - 2.f * f2) * rd2;
}

extern "C" void kernel_launch(void* const* d_in, const int* in_sizes, int n_in,
                              void* d_out, int out_size, void* d_ws, size_t ws_size,
                              hipStream_t stream) {
    const float* mask = (const float*)d_in[0];
    const float* edge = (const float*)d_in[1];
    float* out = (float*)d_out;

    float* csum = (float*)d_ws;             // [B*C,H,W]  11.3 MB
    float* dcol = csum + (size_t)B * C * HW;  // [B,H,W]  0.57 MB
    float* rDg  = dcol + B * HW;              // [B,H,W]  0.57 MB

    const int colgrid = B * C * 3;          // 228 blocks x 512
    const int rowgrid = (B * C * H) / 4;    // 3648 blocks x 256

    // iter 0: mask -> out (also computes dcol and rD)
    k_col<true><<<colgrid, 512, 0, stream>>>(mask, edge, csum, dcol);
    k_row<true><<<rowgrid, 256, 0, stream>>>(mask, out, edge, csum, dcol, rDg);
    // iter 1: out -> out
    k_col<false><<<colgrid, 512, 0, stream>>>(out, edge, csum, nullptr);
    k_row<false><<<rowgrid, 256, 0, stream>>>(out, out, edge, csum, nullptr, rDg);
    // iter 2: out -> out
    k_col<false><<<colgrid, 512, 0, stream>>>(out, edge, csum, nullptr);
    k_row<false><<<rowgrid, 256, 0, stream>>>(out, out, edge, csum, nullptr, rDg);
}